// Round 12
// baseline (827.302 us; speedup 1.0000x reference)
//
#include <hip/hip_runtime.h>

// SpikeLinear: out = LIF_scan( x @ W^T + bias ) over T=8 timesteps.
//
// Numerics (DO NOT CHANGE): must reproduce numpy/OpenBLAS sgemm bit-for-bit
// because the spike threshold (memb > 1.0) is discontinuous. OpenBLAS
// accumulates each C element as a strict sequential fp32 FMA chain over
// ascending k, blocked by kc=384: each panel accumulates from zero in
// registers, then C += panel (fp32 add) in ascending panel order, then fp32
// bias add and fp32 LIF scan. Verified absmax == 0.0 in rounds 3, 8-11.
//
// Perf lineage:
//  r9/r10: K-split panels; LDS-read-pipe bound. r11: v_pk_fma_f32 (2 fp32
//  FMA/inst, bit-identical per-component) -> 811us total, but LDS still
//  binding: every wave read the FULL 256-col W stripe per k (4-way bank
//  conflict on the tx*16B-stride read, 2.7e7 conflict cycles/dispatch).
//  r12 (this): wave-sliced mapping. Wave w owns cols [64w,64w+64); lane =
//  (rg=lane>>3, cg=lane&7); thread owns 8 CONSECUTIVE cols (wv*64+cg*8)
//  and its batch's 8 t-rows. Each ds_read_b128 now touches 128 distinct
//  bytes (8-way broadcast free, 2-way bank alias free) -> per-wave distinct
//  LDS bytes per k halved, 4-way conflicts eliminated. FMA loop unchanged.

typedef float v2f __attribute__((ext_vector_type(2)));

// acc = x.word0 * w + acc   (x broadcast from word0 of the pair)
#define PK_LO(a, x, wv)                                                       \
    asm("v_pk_fma_f32 %0, %1, %2, %0 op_sel:[0,0,0] op_sel_hi:[0,1,1]"        \
        : "+v"(a) : "v"(x), "v"(wv))
// acc = x.word1 * w + acc   (x broadcast from word1 of the pair)
#define PK_HI(a, x, wv)                                                       \
    asm("v_pk_fma_f32 %0, %1, %2, %0 op_sel:[1,0,0] op_sel_hi:[1,1,1]"        \
        : "+v"(a) : "v"(x), "v"(wv))

constexpr int TSTEPS = 8;
constexpr int BK     = 16;
constexpr int TILE_M = 64;    // 8 batches * 8 timesteps
constexpr int TILE_NP= 256;   // panel-kernel tile: 4 waves x 64 cols
constexpr int TILE_N = 128;   // fallback-kernel tile
constexpr int KC     = 384;   // OpenBLAS SGEMM_DEFAULT_Q on x86-64

// ---------------------------------------------------------------- phase 1 --
__global__ __launch_bounds__(256, 2)
void spike_panel_gemm(const float* __restrict__ x,
                      const float* __restrict__ w,
                      float* __restrict__ panels,   // ws: panels 0..np-2, NW cols
                      float* __restrict__ out,      // last panel, spike layout
                      int slice0, int NW,
                      int B, int IN, int OUT, int npanels)
{
    __shared__ float xs[BK][TILE_M + 4];
    __shared__ float wsh[BK][TILE_NP + 8];

    const int tid  = threadIdx.x;
    const int lane = tid & 63;
    const int wv   = tid >> 6;       // wave 0..3 -> col strip [64w, 64w+64)
    const int rg   = lane >> 3;      // row octet 0..7 -> batch within tile
    const int cg   = lane & 7;       // col octet 0..7 -> 8 consecutive cols
    const int cbase = wv * 64 + cg * 8;   // col within tile

    const int m0 = blockIdx.y * TILE_M;
    const int n0 = slice0 + blockIdx.x * TILE_NP;
    const int p  = blockIdx.z;
    const int ks = p * KC;
    const int ke = (ks + KC < IN) ? (ks + KC) : IN;

    // acc[t][q]: cols cbase+2q, cbase+2q+1 (8 consecutive cols per thread)
    v2f acc[TSTEPS][4];
    #pragma unroll
    for (int t = 0; t < TSTEPS; ++t)
        #pragma unroll
        for (int q = 0; q < 4; ++q) acc[t][q] = (v2f){0.f, 0.f};

    const int sr = tid >> 2;         // 0..63
    const int sk = (tid & 3) * 4;    // 0,4,8,12

    const float* xrow  = x + (size_t)(m0 + sr) * IN + sk;
    const float* wrow0 = w + (size_t)(n0 +       sr) * IN + sk;
    const float* wrow1 = w + (size_t)(n0 +  64 + sr) * IN + sk;
    const float* wrow2 = w + (size_t)(n0 + 128 + sr) * IN + sk;
    const float* wrow3 = w + (size_t)(n0 + 192 + sr) * IN + sk;

    for (int kk = ks; kk < ke; kk += BK) {
        const float4 xv  = *(const float4*)(xrow  + kk);
        const float4 wv0 = *(const float4*)(wrow0 + kk);
        const float4 wv1 = *(const float4*)(wrow1 + kk);
        const float4 wv2 = *(const float4*)(wrow2 + kk);
        const float4 wv3 = *(const float4*)(wrow3 + kk);
        __syncthreads();
        xs[sk+0][sr] = xv.x;  xs[sk+1][sr] = xv.y;
        xs[sk+2][sr] = xv.z;  xs[sk+3][sr] = xv.w;
        wsh[sk+0][sr]     = wv0.x; wsh[sk+1][sr]     = wv0.y;
        wsh[sk+2][sr]     = wv0.z; wsh[sk+3][sr]     = wv0.w;
        wsh[sk+0][sr+64]  = wv1.x; wsh[sk+1][sr+64]  = wv1.y;
        wsh[sk+2][sr+64]  = wv1.z; wsh[sk+3][sr+64]  = wv1.w;
        wsh[sk+0][sr+128] = wv2.x; wsh[sk+1][sr+128] = wv2.y;
        wsh[sk+2][sr+128] = wv2.z; wsh[sk+3][sr+128] = wv2.w;
        wsh[sk+0][sr+192] = wv3.x; wsh[sk+1][sr+192] = wv3.y;
        wsh[sk+2][sr+192] = wv3.z; wsh[sk+3][sr+192] = wv3.w;
        __syncthreads();

        #pragma unroll
        for (int k = 0; k < BK; ++k) {
            // xp[tp] = {x[2tp], x[2tp+1]} for this thread's batch row
            v2f xp[4], wva[4];
            *(float4*)&xp[0]  = *(const float4*)&xs[k][rg*8];
            *(float4*)&xp[2]  = *(const float4*)&xs[k][rg*8 + 4];
            *(float4*)&wva[0] = *(const float4*)&wsh[k][cbase];
            *(float4*)&wva[2] = *(const float4*)&wsh[k][cbase + 4];
            #pragma unroll
            for (int tp = 0; tp < 4; ++tp) {
                #pragma unroll
                for (int q = 0; q < 4; ++q) {
                    PK_LO(acc[2*tp  ][q], xp[tp], wva[q]);
                    PK_HI(acc[2*tp+1][q], xp[tp], wva[q]);
                }
            }
        }
    }

    const int bg = blockIdx.y * 8 + rg;             // global batch index
    const int cs = blockIdx.x * TILE_NP + cbase;    // col within slice
    if (p < npanels - 1) {
        // panels 0..np-2: m-major rows (b*8 + t), NW-wide, slot p in ws
        float* pb = panels + ((size_t)p * B * TSTEPS) * NW;
        #pragma unroll
        for (int t = 0; t < TSTEPS; ++t) {
            const int m = bg * TSTEPS + t;
            float4 lo, hi;
            *(v2f*)&lo.x = acc[t][0]; *(v2f*)&lo.z = acc[t][1];
            *(v2f*)&hi.x = acc[t][2]; *(v2f*)&hi.z = acc[t][3];
            *(float4*)(pb + (size_t)m * NW + cs)     = lo;
            *(float4*)(pb + (size_t)m * NW + cs + 4) = hi;
        }
    } else {
        // last panel -> out with SPIKE row mapping (t*B + b): phase 2's
        // reader thread == writer thread (no cross-thread hazard).
        const int o0 = n0 + cbase;
        #pragma unroll
        for (int t = 0; t < TSTEPS; ++t) {
            float4 lo, hi;
            *(v2f*)&lo.x = acc[t][0]; *(v2f*)&lo.z = acc[t][1];
            *(v2f*)&hi.x = acc[t][2]; *(v2f*)&hi.z = acc[t][3];
            float* op = out + ((size_t)t * B + bg) * OUT + o0;
            *(float4*)op       = lo;
            *(float4*)(op + 4) = hi;
        }
    }
}

// ---------------------------------------------------------------- phase 2 --
__global__ __launch_bounds__(256)
void spike_fold_scan(const float* __restrict__ panels,
                     const float* __restrict__ bias,
                     float* __restrict__ out,
                     int slice0, int NW,
                     int B, int OUT, int npanels)
{
    const int b = blockIdx.y;
    const size_t psz = (size_t)B * TSTEPS * NW;
    const int nc4 = NW / 4;

    for (int c4 = blockIdx.x * 256 + threadIdx.x; c4 < nc4;
         c4 += gridDim.x * 256) {
        const int cs   = c4 * 4;          // col within slice
        const int gcol = slice0 + cs;     // global col

        // v = panel0; v += panel1 ... += panel(np-2)  (exact BLAS order)
        float4 v[TSTEPS];
        #pragma unroll
        for (int t = 0; t < TSTEPS; ++t)
            v[t] = *(const float4*)(panels + (size_t)(b*TSTEPS + t) * NW + cs);
        for (int p = 1; p < npanels - 1; ++p) {
            const float* pb = panels + (size_t)p * psz;
            #pragma unroll
            for (int t = 0; t < TSTEPS; ++t) {
                const float4 u = *(const float4*)(pb + (size_t)(b*TSTEPS + t) * NW + cs);
                v[t].x += u.x; v[t].y += u.y; v[t].z += u.z; v[t].w += u.w;
            }
        }
        // last panel from out (spike layout, owned by this thread)
        #pragma unroll
        for (int t = 0; t < TSTEPS; ++t) {
            const float4 u = *(const float4*)(out + ((size_t)t * B + b) * OUT + gcol);
            v[t].x += u.x; v[t].y += u.y; v[t].z += u.z; v[t].w += u.w;
        }

        const float4 bb = *(const float4*)(bias + gcol);
        float memb[4] = {0.f, 0.f, 0.f, 0.f};
        #pragma unroll
        for (int t = 0; t < TSTEPS; ++t) {
            float pre[4] = {v[t].x + bb.x, v[t].y + bb.y,
                            v[t].z + bb.z, v[t].w + bb.w};
            float4 sp;
            float* spp = (float*)&sp;
            #pragma unroll
            for (int c = 0; c < 4; ++c) {
                memb[c] += pre[c];                       // VTHR = 1.0 (exact)
                float s = (memb[c] > 1.0f) ? 1.0f : 0.0f;
                memb[c] *= (1.0f - s);                   // reset to zero
                spp[c] = s;
            }
            *(float4*)(out + ((size_t)t * B + b) * OUT + gcol) = sp;
        }
    }
}

// ------------------------------------------------- fallback: r3 (verified) --
__global__ __launch_bounds__(256, 4)
void spike_linear_f32seq(const float* __restrict__ x,
                         const float* __restrict__ w,
                         const float* __restrict__ bias,
                         float* __restrict__ out,
                         int B, int IN, int OUT)
{
    __shared__ float xs[BK][TILE_M + 4];
    __shared__ float ws[BK][TILE_N + 4];

    const int tid = threadIdx.x;
    const int tx  = tid & 31;
    const int ty  = tid >> 5;

    const int m0 = blockIdx.y * TILE_M;
    const int n0 = blockIdx.x * TILE_N;

    float acc_tot[TSTEPS][4];
    float acc_blk[TSTEPS][4];
    #pragma unroll
    for (int t = 0; t < TSTEPS; ++t)
        #pragma unroll
        for (int c = 0; c < 4; ++c) { acc_tot[t][c] = 0.f; acc_blk[t][c] = 0.f; }

    const int sr = tid >> 2;
    const int sk = (tid & 3) * 4;

    const float* xrow  = x + (size_t)(m0 + sr) * IN + sk;
    const float* wrow0 = w + (size_t)(n0 + sr) * IN + sk;
    const float* wrow1 = w + (size_t)(n0 + 64 + sr) * IN + sk;

    for (int kk = 0; kk < IN; kk += BK) {
        if (kk > 0 && (kk % KC) == 0) {
            #pragma unroll
            for (int t = 0; t < TSTEPS; ++t)
                #pragma unroll
                for (int c = 0; c < 4; ++c) {
                    acc_tot[t][c] += acc_blk[t][c];
                    acc_blk[t][c] = 0.f;
                }
        }
        const float4 xv  = *(const float4*)(xrow  + kk);
        const float4 wv0 = *(const float4*)(wrow0 + kk);
        const float4 wv1 = *(const float4*)(wrow1 + kk);
        __syncthreads();
        xs[sk+0][sr] = xv.x;  xs[sk+1][sr] = xv.y;
        xs[sk+2][sr] = xv.z;  xs[sk+3][sr] = xv.w;
        ws[sk+0][sr]    = wv0.x; ws[sk+1][sr]    = wv0.y;
        ws[sk+2][sr]    = wv0.z; ws[sk+3][sr]    = wv0.w;
        ws[sk+0][sr+64] = wv1.x; ws[sk+1][sr+64] = wv1.y;
        ws[sk+2][sr+64] = wv1.z; ws[sk+3][sr+64] = wv1.w;
        __syncthreads();

        #pragma unroll
        for (int k = 0; k < BK; ++k) {
            float xr[TSTEPS];
            *(float4*)&xr[0] = *(const float4*)&xs[k][ty*8];
            *(float4*)&xr[4] = *(const float4*)&xs[k][ty*8 + 4];
            float wr[4];
            *(float4*)&wr[0] = *(const float4*)&ws[k][tx*4];
            #pragma unroll
            for (int t = 0; t < TSTEPS; ++t)
                #pragma unroll
                for (int c = 0; c < 4; ++c)
                    acc_blk[t][c] = fmaf(xr[t], wr[c], acc_blk[t][c]);
        }
    }
    #pragma unroll
    for (int t = 0; t < TSTEPS; ++t)
        #pragma unroll
        for (int c = 0; c < 4; ++c)
            acc_tot[t][c] += acc_blk[t][c];

    const int bg = blockIdx.y * 8 + ty;
    const int o0 = n0 + tx * 4;
    const float4 bv = *(const float4*)(bias + o0);
    const float bb[4] = {bv.x, bv.y, bv.z, bv.w};
    float memb[4] = {0.f, 0.f, 0.f, 0.f};
    #pragma unroll
    for (int t = 0; t < TSTEPS; ++t) {
        float4 sp;
        float* spp = (float*)&sp;
        #pragma unroll
        for (int c = 0; c < 4; ++c) {
            float pre = acc_tot[t][c] + bb[c];
            memb[c] += pre;
            float s = (memb[c] > 1.0f) ? 1.0f : 0.0f;
            memb[c] *= (1.0f - s);
            spp[c] = s;
        }
        *(float4*)(out + ((size_t)t * B + bg) * OUT + o0) = sp;
    }
}

extern "C" void kernel_launch(void* const* d_in, const int* in_sizes, int n_in,
                              void* d_out, int out_size, void* d_ws, size_t ws_size,
                              hipStream_t stream)
{
    const float* x    = (const float*)d_in[0];
    const float* w    = (const float*)d_in[1];
    const float* bias = (const float*)d_in[2];
    float* out = (float*)d_out;

    const int OUT = in_sizes[2];            // 4096
    const int IN  = in_sizes[1] / OUT;      // 4096
    const int BT  = in_sizes[0] / IN;       // 2048
    const int B   = BT / TSTEPS;            // 256

    const int npanels = (IN + KC - 1) / KC; // 11

    // pick the widest column slice whose panel storage fits ws
    int NW = 0;
    for (int cand = 4096; cand >= 256; cand >>= 1) {
        if ((OUT % cand) == 0 &&
            (size_t)(npanels - 1) * BT * cand * sizeof(float) <= ws_size) {
            NW = cand;
            break;
        }
    }

    if (NW >= 256 && npanels >= 2) {
        float* panels = (float*)d_ws;
        const int nslices = OUT / NW;
        for (int s = 0; s < nslices; ++s) {
            const int slice0 = s * NW;
            dim3 g1(NW / TILE_NP, BT / TILE_M, npanels);
            spike_panel_gemm<<<g1, 256, 0, stream>>>(x, w, panels, out,
                                                     slice0, NW, B, IN, OUT,
                                                     npanels);
            int gx = NW / 1024; if (gx < 1) gx = 1;
            dim3 g2(gx, B);
            spike_fold_scan<<<g2, 256, 0, stream>>>(panels, bias, out,
                                                    slice0, NW, B, OUT,
                                                    npanels);
        }
    } else {
        dim3 grid(OUT / TILE_N, BT / TILE_M);          // (32, 32)
        spike_linear_f32seq<<<grid, 256, 0, stream>>>(x, w, bias, out, B, IN, OUT);
    }
}

// Round 13
// 800.586 us; speedup vs baseline: 1.0334x; 1.0334x over previous
//
#include <hip/hip_runtime.h>

// SpikeLinear: out = LIF_scan( x @ W^T + bias ) over T=8 timesteps.
//
// Numerics (DO NOT CHANGE): must reproduce numpy/OpenBLAS sgemm bit-for-bit
// because the spike threshold (memb > 1.0) is discontinuous. OpenBLAS
// accumulates each C element as a strict sequential fp32 FMA chain over
// ascending k, blocked by kc=384: each panel accumulates from zero in
// registers, then C += panel (fp32 add) in ascending panel order, then fp32
// bias add and fp32 LIF scan. Verified absmax == 0.0 in rounds 3, 8-12.
//
// Perf lineage:
//  r11: v_pk_fma_f32 -> 811us. r12: read remap -> no change; conflict count
//  IDENTICAL across r10-r12 => conflicts are the STAGING WRITES (wsh row
//  stride 264 == 8 mod 32 -> all four sk groups hit one bank = 4-way).
//  r13 (this):
//   (1) wsh stride 260 (==4 mod 32): staging writes exactly 2 lanes/bank
//       (free per m136). xs (stride 68) was already fine.
//   (2) thread cols {wv*64+cg*4 .. +3} and {+32..}: wsh b128 reads hit 8
//       distinct 4-bank groups per quarter-wave -> conflict-free.
//   (3) prefetch: issue step s+1's global loads AFTER the write barrier so
//       the 2048-cycle FMA block covers HBM/L2 latency (the old schedule
//       exposed vmcnt between load-issue and LDS-write). Panel kernel has
//       no acc_tot, so +20 prefetch VGPRs stays under the 128 cap (r6/r7's
//       spill trap came from the dual accumulator set).

typedef float v2f __attribute__((ext_vector_type(2)));

// acc = x.word0 * w + acc   (x broadcast from word0 of the pair)
#define PK_LO(a, x, wv)                                                       \
    asm("v_pk_fma_f32 %0, %1, %2, %0 op_sel:[0,0,0] op_sel_hi:[0,1,1]"        \
        : "+v"(a) : "v"(x), "v"(wv))
// acc = x.word1 * w + acc   (x broadcast from word1 of the pair)
#define PK_HI(a, x, wv)                                                       \
    asm("v_pk_fma_f32 %0, %1, %2, %0 op_sel:[1,0,0] op_sel_hi:[1,1,1]"        \
        : "+v"(a) : "v"(x), "v"(wv))

constexpr int TSTEPS = 8;
constexpr int BK     = 16;
constexpr int TILE_M = 64;    // 8 batches * 8 timesteps
constexpr int TILE_NP= 256;   // panel-kernel tile: 4 waves x 64 cols
constexpr int TILE_N = 128;   // fallback-kernel tile
constexpr int KC     = 384;   // OpenBLAS SGEMM_DEFAULT_Q on x86-64
constexpr int WS_PAD = 4;     // wsh row stride 260 == 4 mod 32 (bank spread)

// ---------------------------------------------------------------- phase 1 --
__global__ __launch_bounds__(256, 2)
void spike_panel_gemm(const float* __restrict__ x,
                      const float* __restrict__ w,
                      float* __restrict__ panels,   // ws: panels 0..np-2, NW cols
                      float* __restrict__ out,      // last panel, spike layout
                      int slice0, int NW,
                      int B, int IN, int OUT, int npanels)
{
    __shared__ float xs[BK][TILE_M + 4];
    __shared__ float wsh[BK][TILE_NP + WS_PAD];

    const int tid  = threadIdx.x;
    const int lane = tid & 63;
    const int wv   = tid >> 6;       // wave 0..3 -> col strip [64w, 64w+64)
    const int rg   = lane >> 3;      // row octet 0..7 -> batch within tile
    const int cg   = lane & 7;       // col quad index
    const int clo  = wv * 64 + cg * 4;      // cols clo..clo+3 and clo+32..+35

    const int m0 = blockIdx.y * TILE_M;
    const int n0 = slice0 + blockIdx.x * TILE_NP;
    const int p  = blockIdx.z;
    const int ks = p * KC;
    const int ke = (ks + KC < IN) ? (ks + KC) : IN;

    // acc[t][q]: q=0,1 -> cols {clo..+3}; q=2,3 -> cols {clo+32..+35}
    v2f acc[TSTEPS][4];
    #pragma unroll
    for (int t = 0; t < TSTEPS; ++t)
        #pragma unroll
        for (int q = 0; q < 4; ++q) acc[t][q] = (v2f){0.f, 0.f};

    const int sr = tid >> 2;         // 0..63
    const int sk = (tid & 3) * 4;    // 0,4,8,12

    const float* xrow  = x + (size_t)(m0 + sr) * IN + sk;
    const float* wrow0 = w + (size_t)(n0 +       sr) * IN + sk;
    const float* wrow1 = w + (size_t)(n0 +  64 + sr) * IN + sk;
    const float* wrow2 = w + (size_t)(n0 + 128 + sr) * IN + sk;
    const float* wrow3 = w + (size_t)(n0 + 192 + sr) * IN + sk;

    const int nsteps = (ke - ks) / BK;

    // prologue: load step 0 into prefetch registers
    float4 xv  = *(const float4*)(xrow  + ks);
    float4 wv0 = *(const float4*)(wrow0 + ks);
    float4 wv1 = *(const float4*)(wrow1 + ks);
    float4 wv2 = *(const float4*)(wrow2 + ks);
    float4 wv3 = *(const float4*)(wrow3 + ks);

    for (int s = 0; s < nsteps; ++s) {
        __syncthreads();
        xs[sk+0][sr] = xv.x;  xs[sk+1][sr] = xv.y;
        xs[sk+2][sr] = xv.z;  xs[sk+3][sr] = xv.w;
        wsh[sk+0][sr]     = wv0.x; wsh[sk+1][sr]     = wv0.y;
        wsh[sk+2][sr]     = wv0.z; wsh[sk+3][sr]     = wv0.w;
        wsh[sk+0][sr+64]  = wv1.x; wsh[sk+1][sr+64]  = wv1.y;
        wsh[sk+2][sr+64]  = wv1.z; wsh[sk+3][sr+64]  = wv1.w;
        wsh[sk+0][sr+128] = wv2.x; wsh[sk+1][sr+128] = wv2.y;
        wsh[sk+2][sr+128] = wv2.z; wsh[sk+3][sr+128] = wv2.w;
        wsh[sk+0][sr+192] = wv3.x; wsh[sk+1][sr+192] = wv3.y;
        wsh[sk+2][sr+192] = wv3.z; wsh[sk+3][sr+192] = wv3.w;
        __syncthreads();

        // prefetch step s+1: latency hides under the 16-k FMA block below
        if (s + 1 < nsteps) {
            const int ko = ks + (s + 1) * BK;
            xv  = *(const float4*)(xrow  + ko);
            wv0 = *(const float4*)(wrow0 + ko);
            wv1 = *(const float4*)(wrow1 + ko);
            wv2 = *(const float4*)(wrow2 + ko);
            wv3 = *(const float4*)(wrow3 + ko);
        }

        #pragma unroll
        for (int k = 0; k < BK; ++k) {
            // xp[tp] = {x[2tp], x[2tp+1]} for this thread's batch row
            v2f xp[4], wva[4];
            *(float4*)&xp[0]  = *(const float4*)&xs[k][rg*8];
            *(float4*)&xp[2]  = *(const float4*)&xs[k][rg*8 + 4];
            *(float4*)&wva[0] = *(const float4*)&wsh[k][clo];
            *(float4*)&wva[2] = *(const float4*)&wsh[k][clo + 32];
            #pragma unroll
            for (int tp = 0; tp < 4; ++tp) {
                #pragma unroll
                for (int q = 0; q < 4; ++q) {
                    PK_LO(acc[2*tp  ][q], xp[tp], wva[q]);
                    PK_HI(acc[2*tp+1][q], xp[tp], wva[q]);
                }
            }
        }
    }

    const int bg = blockIdx.y * 8 + rg;            // global batch index
    const int cs = blockIdx.x * TILE_NP + clo;     // col within slice
    if (p < npanels - 1) {
        // panels 0..np-2: m-major rows (b*8 + t), NW-wide, slot p in ws
        float* pb = panels + ((size_t)p * B * TSTEPS) * NW;
        #pragma unroll
        for (int t = 0; t < TSTEPS; ++t) {
            const int m = bg * TSTEPS + t;
            float4 lo, hi;
            *(v2f*)&lo.x = acc[t][0]; *(v2f*)&lo.z = acc[t][1];
            *(v2f*)&hi.x = acc[t][2]; *(v2f*)&hi.z = acc[t][3];
            *(float4*)(pb + (size_t)m * NW + cs)      = lo;
            *(float4*)(pb + (size_t)m * NW + cs + 32) = hi;
        }
    } else {
        // last panel -> out with SPIKE row mapping (t*B + b): phase 2's
        // reader thread == writer thread (no cross-thread hazard).
        const int o0 = n0 + clo;
        #pragma unroll
        for (int t = 0; t < TSTEPS; ++t) {
            float4 lo, hi;
            *(v2f*)&lo.x = acc[t][0]; *(v2f*)&lo.z = acc[t][1];
            *(v2f*)&hi.x = acc[t][2]; *(v2f*)&hi.z = acc[t][3];
            float* op = out + ((size_t)t * B + bg) * OUT + o0;
            *(float4*)op        = lo;
            *(float4*)(op + 32) = hi;
        }
    }
}

// ---------------------------------------------------------------- phase 2 --
__global__ __launch_bounds__(256)
void spike_fold_scan(const float* __restrict__ panels,
                     const float* __restrict__ bias,
                     float* __restrict__ out,
                     int slice0, int NW,
                     int B, int OUT, int npanels)
{
    const int b = blockIdx.y;
    const size_t psz = (size_t)B * TSTEPS * NW;
    const int nc4 = NW / 4;

    for (int c4 = blockIdx.x * 256 + threadIdx.x; c4 < nc4;
         c4 += gridDim.x * 256) {
        const int cs   = c4 * 4;          // col within slice
        const int gcol = slice0 + cs;     // global col

        // v = panel0; v += panel1 ... += panel(np-2)  (exact BLAS order)
        float4 v[TSTEPS];
        #pragma unroll
        for (int t = 0; t < TSTEPS; ++t)
            v[t] = *(const float4*)(panels + (size_t)(b*TSTEPS + t) * NW + cs);
        for (int p = 1; p < npanels - 1; ++p) {
            const float* pb = panels + (size_t)p * psz;
            #pragma unroll
            for (int t = 0; t < TSTEPS; ++t) {
                const float4 u = *(const float4*)(pb + (size_t)(b*TSTEPS + t) * NW + cs);
                v[t].x += u.x; v[t].y += u.y; v[t].z += u.z; v[t].w += u.w;
            }
        }
        // last panel from out (spike layout, owned by this thread)
        #pragma unroll
        for (int t = 0; t < TSTEPS; ++t) {
            const float4 u = *(const float4*)(out + ((size_t)t * B + b) * OUT + gcol);
            v[t].x += u.x; v[t].y += u.y; v[t].z += u.z; v[t].w += u.w;
        }

        const float4 bb = *(const float4*)(bias + gcol);
        float memb[4] = {0.f, 0.f, 0.f, 0.f};
        #pragma unroll
        for (int t = 0; t < TSTEPS; ++t) {
            float pre[4] = {v[t].x + bb.x, v[t].y + bb.y,
                            v[t].z + bb.z, v[t].w + bb.w};
            float4 sp;
            float* spp = (float*)&sp;
            #pragma unroll
            for (int c = 0; c < 4; ++c) {
                memb[c] += pre[c];                       // VTHR = 1.0 (exact)
                float s = (memb[c] > 1.0f) ? 1.0f : 0.0f;
                memb[c] *= (1.0f - s);                   // reset to zero
                spp[c] = s;
            }
            *(float4*)(out + ((size_t)t * B + b) * OUT + gcol) = sp;
        }
    }
}

// ------------------------------------------------- fallback: r3 (verified) --
__global__ __launch_bounds__(256, 4)
void spike_linear_f32seq(const float* __restrict__ x,
                         const float* __restrict__ w,
                         const float* __restrict__ bias,
                         float* __restrict__ out,
                         int B, int IN, int OUT)
{
    __shared__ float xs[BK][TILE_M + 4];
    __shared__ float ws[BK][TILE_N + 4];

    const int tid = threadIdx.x;
    const int tx  = tid & 31;
    const int ty  = tid >> 5;

    const int m0 = blockIdx.y * TILE_M;
    const int n0 = blockIdx.x * TILE_N;

    float acc_tot[TSTEPS][4];
    float acc_blk[TSTEPS][4];
    #pragma unroll
    for (int t = 0; t < TSTEPS; ++t)
        #pragma unroll
        for (int c = 0; c < 4; ++c) { acc_tot[t][c] = 0.f; acc_blk[t][c] = 0.f; }

    const int sr = tid >> 2;
    const int sk = (tid & 3) * 4;

    const float* xrow  = x + (size_t)(m0 + sr) * IN + sk;
    const float* wrow0 = w + (size_t)(n0 + sr) * IN + sk;
    const float* wrow1 = w + (size_t)(n0 + 64 + sr) * IN + sk;

    for (int kk = 0; kk < IN; kk += BK) {
        if (kk > 0 && (kk % KC) == 0) {
            #pragma unroll
            for (int t = 0; t < TSTEPS; ++t)
                #pragma unroll
                for (int c = 0; c < 4; ++c) {
                    acc_tot[t][c] += acc_blk[t][c];
                    acc_blk[t][c] = 0.f;
                }
        }
        const float4 xv  = *(const float4*)(xrow  + kk);
        const float4 wv0 = *(const float4*)(wrow0 + kk);
        const float4 wv1 = *(const float4*)(wrow1 + kk);
        __syncthreads();
        xs[sk+0][sr] = xv.x;  xs[sk+1][sr] = xv.y;
        xs[sk+2][sr] = xv.z;  xs[sk+3][sr] = xv.w;
        ws[sk+0][sr]    = wv0.x; ws[sk+1][sr]    = wv0.y;
        ws[sk+2][sr]    = wv0.z; ws[sk+3][sr]    = wv0.w;
        ws[sk+0][sr+64] = wv1.x; ws[sk+1][sr+64] = wv1.y;
        ws[sk+2][sr+64] = wv1.z; ws[sk+3][sr+64] = wv1.w;
        __syncthreads();

        #pragma unroll
        for (int k = 0; k < BK; ++k) {
            float xr[TSTEPS];
            *(float4*)&xr[0] = *(const float4*)&xs[k][ty*8];
            *(float4*)&xr[4] = *(const float4*)&xs[k][ty*8 + 4];
            float wr[4];
            *(float4*)&wr[0] = *(const float4*)&ws[k][tx*4];
            #pragma unroll
            for (int t = 0; t < TSTEPS; ++t)
                #pragma unroll
                for (int c = 0; c < 4; ++c)
                    acc_blk[t][c] = fmaf(xr[t], wr[c], acc_blk[t][c]);
        }
    }
    #pragma unroll
    for (int t = 0; t < TSTEPS; ++t)
        #pragma unroll
        for (int c = 0; c < 4; ++c)
            acc_tot[t][c] += acc_blk[t][c];

    const int bg = blockIdx.y * 8 + ty;
    const int o0 = n0 + tx * 4;
    const float4 bv = *(const float4*)(bias + o0);
    const float bb[4] = {bv.x, bv.y, bv.z, bv.w};
    float memb[4] = {0.f, 0.f, 0.f, 0.f};
    #pragma unroll
    for (int t = 0; t < TSTEPS; ++t) {
        float4 sp;
        float* spp = (float*)&sp;
        #pragma unroll
        for (int c = 0; c < 4; ++c) {
            float pre = acc_tot[t][c] + bb[c];
            memb[c] += pre;
            float s = (memb[c] > 1.0f) ? 1.0f : 0.0f;
            memb[c] *= (1.0f - s);
            spp[c] = s;
        }
        *(float4*)(out + ((size_t)t * B + bg) * OUT + o0) = sp;
    }
}

extern "C" void kernel_launch(void* const* d_in, const int* in_sizes, int n_in,
                              void* d_out, int out_size, void* d_ws, size_t ws_size,
                              hipStream_t stream)
{
    const float* x    = (const float*)d_in[0];
    const float* w    = (const float*)d_in[1];
    const float* bias = (const float*)d_in[2];
    float* out = (float*)d_out;

    const int OUT = in_sizes[2];            // 4096
    const int IN  = in_sizes[1] / OUT;      // 4096
    const int BT  = in_sizes[0] / IN;       // 2048
    const int B   = BT / TSTEPS;            // 256

    const int npanels = (IN + KC - 1) / KC; // 11

    // pick the widest column slice whose panel storage fits ws
    int NW = 0;
    for (int cand = 4096; cand >= 256; cand >>= 1) {
        if ((OUT % cand) == 0 &&
            (size_t)(npanels - 1) * BT * cand * sizeof(float) <= ws_size) {
            NW = cand;
            break;
        }
    }

    if (NW >= 256 && npanels >= 2) {
        float* panels = (float*)d_ws;
        const int nslices = OUT / NW;
        for (int s = 0; s < nslices; ++s) {
            const int slice0 = s * NW;
            dim3 g1(NW / TILE_NP, BT / TILE_M, npanels);
            spike_panel_gemm<<<g1, 256, 0, stream>>>(x, w, panels, out,
                                                     slice0, NW, B, IN, OUT,
                                                     npanels);
            int gx = NW / 1024; if (gx < 1) gx = 1;
            dim3 g2(gx, B);
            spike_fold_scan<<<g2, 256, 0, stream>>>(panels, bias, out,
                                                    slice0, NW, B, OUT,
                                                    npanels);
        }
    } else {
        dim3 grid(OUT / TILE_N, BT / TILE_M);          // (32, 32)
        spike_linear_f32seq<<<grid, 256, 0, stream>>>(x, w, bias, out, B, IN, OUT);
    }
}

// Round 14
// 800.206 us; speedup vs baseline: 1.0339x; 1.0005x over previous
//
#include <hip/hip_runtime.h>

// SpikeLinear: out = LIF_scan( x @ W^T + bias ) over T=8 timesteps.
//
// Numerics (DO NOT CHANGE): must reproduce numpy/OpenBLAS sgemm bit-for-bit
// because the spike threshold (memb > 1.0) is discontinuous. OpenBLAS
// accumulates each C element as a strict sequential fp32 FMA chain over
// ascending k, blocked by kc=384: each panel accumulates from zero in
// registers, then C += panel (fp32 add) in ascending panel order, then fp32
// bias add and fp32 LIF scan. Verified absmax == 0.0 in rounds 3, 8-13.
//
// Perf lineage:
//  r11: v_pk_fma_f32 -> 811us. r13: staging-write bank fix (wsh stride 260)
//  + conflict-free read cols + prefetch -> 800us total, 381us/slice,
//  conflicts 2.73e7 -> 1.05e7, VGPR 60, VALUBusy 75%, occupancy 40%.
//  FLOP floor per slice = 218us (157.3 TF); gap = staging VALU (~70us) +
//  barrier/LDS-latency idle (~95us) at only 8 waves/CU ((256,2)).
//  r14 (this): __launch_bounds__(256,4) on the panel kernel ONLY.
//  VGPR 60 fits the 64 cap (no spill expected; r6's spill was natural~75>64),
//  LDS 21KB*4=84KB<160KB. 16 waves/CU hides barrier drain + LDS latency.

typedef float v2f __attribute__((ext_vector_type(2)));

// acc = x.word0 * w + acc   (x broadcast from word0 of the pair)
#define PK_LO(a, x, wv)                                                       \
    asm("v_pk_fma_f32 %0, %1, %2, %0 op_sel:[0,0,0] op_sel_hi:[0,1,1]"        \
        : "+v"(a) : "v"(x), "v"(wv))
// acc = x.word1 * w + acc   (x broadcast from word1 of the pair)
#define PK_HI(a, x, wv)                                                       \
    asm("v_pk_fma_f32 %0, %1, %2, %0 op_sel:[1,0,0] op_sel_hi:[1,1,1]"        \
        : "+v"(a) : "v"(x), "v"(wv))

constexpr int TSTEPS = 8;
constexpr int BK     = 16;
constexpr int TILE_M = 64;    // 8 batches * 8 timesteps
constexpr int TILE_NP= 256;   // panel-kernel tile: 4 waves x 64 cols
constexpr int TILE_N = 128;   // fallback-kernel tile
constexpr int KC     = 384;   // OpenBLAS SGEMM_DEFAULT_Q on x86-64
constexpr int WS_PAD = 4;     // wsh row stride 260 == 4 mod 32 (bank spread)

// ---------------------------------------------------------------- phase 1 --
__global__ __launch_bounds__(256, 4)
void spike_panel_gemm(const float* __restrict__ x,
                      const float* __restrict__ w,
                      float* __restrict__ panels,   // ws: panels 0..np-2, NW cols
                      float* __restrict__ out,      // last panel, spike layout
                      int slice0, int NW,
                      int B, int IN, int OUT, int npanels)
{
    __shared__ float xs[BK][TILE_M + 4];
    __shared__ float wsh[BK][TILE_NP + WS_PAD];

    const int tid  = threadIdx.x;
    const int lane = tid & 63;
    const int wv   = tid >> 6;       // wave 0..3 -> col strip [64w, 64w+64)
    const int rg   = lane >> 3;      // row octet 0..7 -> batch within tile
    const int cg   = lane & 7;       // col quad index
    const int clo  = wv * 64 + cg * 4;      // cols clo..clo+3 and clo+32..+35

    const int m0 = blockIdx.y * TILE_M;
    const int n0 = slice0 + blockIdx.x * TILE_NP;
    const int p  = blockIdx.z;
    const int ks = p * KC;
    const int ke = (ks + KC < IN) ? (ks + KC) : IN;

    // acc[t][q]: q=0,1 -> cols {clo..+3}; q=2,3 -> cols {clo+32..+35}
    v2f acc[TSTEPS][4];
    #pragma unroll
    for (int t = 0; t < TSTEPS; ++t)
        #pragma unroll
        for (int q = 0; q < 4; ++q) acc[t][q] = (v2f){0.f, 0.f};

    const int sr = tid >> 2;         // 0..63
    const int sk = (tid & 3) * 4;    // 0,4,8,12

    const float* xrow  = x + (size_t)(m0 + sr) * IN + sk;
    const float* wrow0 = w + (size_t)(n0 +       sr) * IN + sk;
    const float* wrow1 = w + (size_t)(n0 +  64 + sr) * IN + sk;
    const float* wrow2 = w + (size_t)(n0 + 128 + sr) * IN + sk;
    const float* wrow3 = w + (size_t)(n0 + 192 + sr) * IN + sk;

    const int nsteps = (ke - ks) / BK;

    // prologue: load step 0 into prefetch registers
    float4 xv  = *(const float4*)(xrow  + ks);
    float4 wv0 = *(const float4*)(wrow0 + ks);
    float4 wv1 = *(const float4*)(wrow1 + ks);
    float4 wv2 = *(const float4*)(wrow2 + ks);
    float4 wv3 = *(const float4*)(wrow3 + ks);

    for (int s = 0; s < nsteps; ++s) {
        __syncthreads();
        xs[sk+0][sr] = xv.x;  xs[sk+1][sr] = xv.y;
        xs[sk+2][sr] = xv.z;  xs[sk+3][sr] = xv.w;
        wsh[sk+0][sr]     = wv0.x; wsh[sk+1][sr]     = wv0.y;
        wsh[sk+2][sr]     = wv0.z; wsh[sk+3][sr]     = wv0.w;
        wsh[sk+0][sr+64]  = wv1.x; wsh[sk+1][sr+64]  = wv1.y;
        wsh[sk+2][sr+64]  = wv1.z; wsh[sk+3][sr+64]  = wv1.w;
        wsh[sk+0][sr+128] = wv2.x; wsh[sk+1][sr+128] = wv2.y;
        wsh[sk+2][sr+128] = wv2.z; wsh[sk+3][sr+128] = wv2.w;
        wsh[sk+0][sr+192] = wv3.x; wsh[sk+1][sr+192] = wv3.y;
        wsh[sk+2][sr+192] = wv3.z; wsh[sk+3][sr+192] = wv3.w;
        __syncthreads();

        // prefetch step s+1: latency hides under the 16-k FMA block below
        if (s + 1 < nsteps) {
            const int ko = ks + (s + 1) * BK;
            xv  = *(const float4*)(xrow  + ko);
            wv0 = *(const float4*)(wrow0 + ko);
            wv1 = *(const float4*)(wrow1 + ko);
            wv2 = *(const float4*)(wrow2 + ko);
            wv3 = *(const float4*)(wrow3 + ko);
        }

        #pragma unroll
        for (int k = 0; k < BK; ++k) {
            // xp[tp] = {x[2tp], x[2tp+1]} for this thread's batch row
            v2f xp[4], wva[4];
            *(float4*)&xp[0]  = *(const float4*)&xs[k][rg*8];
            *(float4*)&xp[2]  = *(const float4*)&xs[k][rg*8 + 4];
            *(float4*)&wva[0] = *(const float4*)&wsh[k][clo];
            *(float4*)&wva[2] = *(const float4*)&wsh[k][clo + 32];
            #pragma unroll
            for (int tp = 0; tp < 4; ++tp) {
                #pragma unroll
                for (int q = 0; q < 4; ++q) {
                    PK_LO(acc[2*tp  ][q], xp[tp], wva[q]);
                    PK_HI(acc[2*tp+1][q], xp[tp], wva[q]);
                }
            }
        }
    }

    const int bg = blockIdx.y * 8 + rg;            // global batch index
    const int cs = blockIdx.x * TILE_NP + clo;     // col within slice
    if (p < npanels - 1) {
        // panels 0..np-2: m-major rows (b*8 + t), NW-wide, slot p in ws
        float* pb = panels + ((size_t)p * B * TSTEPS) * NW;
        #pragma unroll
        for (int t = 0; t < TSTEPS; ++t) {
            const int m = bg * TSTEPS + t;
            float4 lo, hi;
            *(v2f*)&lo.x = acc[t][0]; *(v2f*)&lo.z = acc[t][1];
            *(v2f*)&hi.x = acc[t][2]; *(v2f*)&hi.z = acc[t][3];
            *(float4*)(pb + (size_t)m * NW + cs)      = lo;
            *(float4*)(pb + (size_t)m * NW + cs + 32) = hi;
        }
    } else {
        // last panel -> out with SPIKE row mapping (t*B + b): phase 2's
        // reader thread == writer thread (no cross-thread hazard).
        const int o0 = n0 + clo;
        #pragma unroll
        for (int t = 0; t < TSTEPS; ++t) {
            float4 lo, hi;
            *(v2f*)&lo.x = acc[t][0]; *(v2f*)&lo.z = acc[t][1];
            *(v2f*)&hi.x = acc[t][2]; *(v2f*)&hi.z = acc[t][3];
            float* op = out + ((size_t)t * B + bg) * OUT + o0;
            *(float4*)op        = lo;
            *(float4*)(op + 32) = hi;
        }
    }
}

// ---------------------------------------------------------------- phase 2 --
__global__ __launch_bounds__(256)
void spike_fold_scan(const float* __restrict__ panels,
                     const float* __restrict__ bias,
                     float* __restrict__ out,
                     int slice0, int NW,
                     int B, int OUT, int npanels)
{
    const int b = blockIdx.y;
    const size_t psz = (size_t)B * TSTEPS * NW;
    const int nc4 = NW / 4;

    for (int c4 = blockIdx.x * 256 + threadIdx.x; c4 < nc4;
         c4 += gridDim.x * 256) {
        const int cs   = c4 * 4;          // col within slice
        const int gcol = slice0 + cs;     // global col

        // v = panel0; v += panel1 ... += panel(np-2)  (exact BLAS order)
        float4 v[TSTEPS];
        #pragma unroll
        for (int t = 0; t < TSTEPS; ++t)
            v[t] = *(const float4*)(panels + (size_t)(b*TSTEPS + t) * NW + cs);
        for (int p = 1; p < npanels - 1; ++p) {
            const float* pb = panels + (size_t)p * psz;
            #pragma unroll
            for (int t = 0; t < TSTEPS; ++t) {
                const float4 u = *(const float4*)(pb + (size_t)(b*TSTEPS + t) * NW + cs);
                v[t].x += u.x; v[t].y += u.y; v[t].z += u.z; v[t].w += u.w;
            }
        }
        // last panel from out (spike layout, owned by this thread)
        #pragma unroll
        for (int t = 0; t < TSTEPS; ++t) {
            const float4 u = *(const float4*)(out + ((size_t)t * B + b) * OUT + gcol);
            v[t].x += u.x; v[t].y += u.y; v[t].z += u.z; v[t].w += u.w;
        }

        const float4 bb = *(const float4*)(bias + gcol);
        float memb[4] = {0.f, 0.f, 0.f, 0.f};
        #pragma unroll
        for (int t = 0; t < TSTEPS; ++t) {
            float pre[4] = {v[t].x + bb.x, v[t].y + bb.y,
                            v[t].z + bb.z, v[t].w + bb.w};
            float4 sp;
            float* spp = (float*)&sp;
            #pragma unroll
            for (int c = 0; c < 4; ++c) {
                memb[c] += pre[c];                       // VTHR = 1.0 (exact)
                float s = (memb[c] > 1.0f) ? 1.0f : 0.0f;
                memb[c] *= (1.0f - s);                   // reset to zero
                spp[c] = s;
            }
            *(float4*)(out + ((size_t)t * B + b) * OUT + gcol) = sp;
        }
    }
}

// ------------------------------------------------- fallback: r3 (verified) --
__global__ __launch_bounds__(256, 4)
void spike_linear_f32seq(const float* __restrict__ x,
                         const float* __restrict__ w,
                         const float* __restrict__ bias,
                         float* __restrict__ out,
                         int B, int IN, int OUT)
{
    __shared__ float xs[BK][TILE_M + 4];
    __shared__ float ws[BK][TILE_N + 4];

    const int tid = threadIdx.x;
    const int tx  = tid & 31;
    const int ty  = tid >> 5;

    const int m0 = blockIdx.y * TILE_M;
    const int n0 = blockIdx.x * TILE_N;

    float acc_tot[TSTEPS][4];
    float acc_blk[TSTEPS][4];
    #pragma unroll
    for (int t = 0; t < TSTEPS; ++t)
        #pragma unroll
        for (int c = 0; c < 4; ++c) { acc_tot[t][c] = 0.f; acc_blk[t][c] = 0.f; }

    const int sr = tid >> 2;
    const int sk = (tid & 3) * 4;

    const float* xrow  = x + (size_t)(m0 + sr) * IN + sk;
    const float* wrow0 = w + (size_t)(n0 + sr) * IN + sk;
    const float* wrow1 = w + (size_t)(n0 + 64 + sr) * IN + sk;

    for (int kk = 0; kk < IN; kk += BK) {
        if (kk > 0 && (kk % KC) == 0) {
            #pragma unroll
            for (int t = 0; t < TSTEPS; ++t)
                #pragma unroll
                for (int c = 0; c < 4; ++c) {
                    acc_tot[t][c] += acc_blk[t][c];
                    acc_blk[t][c] = 0.f;
                }
        }
        const float4 xv  = *(const float4*)(xrow  + kk);
        const float4 wv0 = *(const float4*)(wrow0 + kk);
        const float4 wv1 = *(const float4*)(wrow1 + kk);
        __syncthreads();
        xs[sk+0][sr] = xv.x;  xs[sk+1][sr] = xv.y;
        xs[sk+2][sr] = xv.z;  xs[sk+3][sr] = xv.w;
        ws[sk+0][sr]    = wv0.x; ws[sk+1][sr]    = wv0.y;
        ws[sk+2][sr]    = wv0.z; ws[sk+3][sr]    = wv0.w;
        ws[sk+0][sr+64] = wv1.x; ws[sk+1][sr+64] = wv1.y;
        ws[sk+2][sr+64] = wv1.z; ws[sk+3][sr+64] = wv1.w;
        __syncthreads();

        #pragma unroll
        for (int k = 0; k < BK; ++k) {
            float xr[TSTEPS];
            *(float4*)&xr[0] = *(const float4*)&xs[k][ty*8];
            *(float4*)&xr[4] = *(const float4*)&xs[k][ty*8 + 4];
            float wr[4];
            *(float4*)&wr[0] = *(const float4*)&ws[k][tx*4];
            #pragma unroll
            for (int t = 0; t < TSTEPS; ++t)
                #pragma unroll
                for (int c = 0; c < 4; ++c)
                    acc_blk[t][c] = fmaf(xr[t], wr[c], acc_blk[t][c]);
        }
    }
    #pragma unroll
    for (int t = 0; t < TSTEPS; ++t)
        #pragma unroll
        for (int c = 0; c < 4; ++c)
            acc_tot[t][c] += acc_blk[t][c];

    const int bg = blockIdx.y * 8 + ty;
    const int o0 = n0 + tx * 4;
    const float4 bv = *(const float4*)(bias + o0);
    const float bb[4] = {bv.x, bv.y, bv.z, bv.w};
    float memb[4] = {0.f, 0.f, 0.f, 0.f};
    #pragma unroll
    for (int t = 0; t < TSTEPS; ++t) {
        float4 sp;
        float* spp = (float*)&sp;
        #pragma unroll
        for (int c = 0; c < 4; ++c) {
            float pre = acc_tot[t][c] + bb[c];
            memb[c] += pre;
            float s = (memb[c] > 1.0f) ? 1.0f : 0.0f;
            memb[c] *= (1.0f - s);
            spp[c] = s;
        }
        *(float4*)(out + ((size_t)t * B + bg) * OUT + o0) = sp;
    }
}

extern "C" void kernel_launch(void* const* d_in, const int* in_sizes, int n_in,
                              void* d_out, int out_size, void* d_ws, size_t ws_size,
                              hipStream_t stream)
{
    const float* x    = (const float*)d_in[0];
    const float* w    = (const float*)d_in[1];
    const float* bias = (const float*)d_in[2];
    float* out = (float*)d_out;

    const int OUT = in_sizes[2];            // 4096
    const int IN  = in_sizes[1] / OUT;      // 4096
    const int BT  = in_sizes[0] / IN;       // 2048
    const int B   = BT / TSTEPS;            // 256

    const int npanels = (IN + KC - 1) / KC; // 11

    // pick the widest column slice whose panel storage fits ws
    int NW = 0;
    for (int cand = 4096; cand >= 256; cand >>= 1) {
        if ((OUT % cand) == 0 &&
            (size_t)(npanels - 1) * BT * cand * sizeof(float) <= ws_size) {
            NW = cand;
            break;
        }
    }

    if (NW >= 256 && npanels >= 2) {
        float* panels = (float*)d_ws;
        const int nslices = OUT / NW;
        for (int s = 0; s < nslices; ++s) {
            const int slice0 = s * NW;
            dim3 g1(NW / TILE_NP, BT / TILE_M, npanels);
            spike_panel_gemm<<<g1, 256, 0, stream>>>(x, w, panels, out,
                                                     slice0, NW, B, IN, OUT,
                                                     npanels);
            int gx = NW / 1024; if (gx < 1) gx = 1;
            dim3 g2(gx, B);
            spike_fold_scan<<<g2, 256, 0, stream>>>(panels, bias, out,
                                                    slice0, NW, B, OUT,
                                                    npanels);
        }
    } else {
        dim3 grid(OUT / TILE_N, BT / TILE_M);          // (32, 32)
        spike_linear_f32seq<<<grid, 256, 0, stream>>>(x, w, bias, out, B, IN, OUT);
    }
}